// Round 5
// baseline (505.799 us; speedup 1.0000x reference)
//
#include <hip/hip_runtime.h>
#include <hip/hip_bf16.h>

typedef unsigned int uint;
typedef unsigned short ushort;

// ---------- helpers ----------
__device__ __forceinline__ float bflo(uint u) { return __uint_as_float(u << 16); }
__device__ __forceinline__ float bfhi(uint u) { return __uint_as_float(u & 0xffff0000u); }
__device__ __forceinline__ float bfu(ushort s) { return __uint_as_float(((uint)s) << 16); }
__device__ __forceinline__ ushort f2bf(float f) {
    uint u = __float_as_uint(f);
    u += 0x7fffu + ((u >> 16) & 1u);   // RNE
    return (ushort)(u >> 16);
}
__device__ __forceinline__ float rlanef(float v, int j) {
    return __int_as_float(__builtin_amdgcn_readlane(__float_as_int(v), j));
}
// sum across 4-lane subgroup (lanes differing in bits 0,1)
__device__ __forceinline__ float red4(float v) {
    v += __shfl_xor(v, 1, 64);
    v += __shfl_xor(v, 2, 64);
    return v;
}
__device__ __forceinline__ float lrelu(float v) { return (v > 0.f) ? v : 0.2f * v; }
__device__ __forceinline__ void unp8(uint4 u, float* f) {
    f[0] = bflo(u.x); f[1] = bfhi(u.x);
    f[2] = bflo(u.y); f[3] = bfhi(u.y);
    f[4] = bflo(u.z); f[5] = bfhi(u.z);
    f[6] = bflo(u.w); f[7] = bfhi(u.w);
}

// ---------- build kernels ----------
__global__ __launch_bounds__(256) void k_zero(int* cnt, float* sumw, int* fill, int n) {
    int i = blockIdx.x * blockDim.x + threadIdx.x;
    if (i < n) { cnt[i] = 0; sumw[i] = 0.f; fill[i] = 0; }
}

__global__ __launch_bounds__(256) void k_count(const int* __restrict__ dst,
                                               const float* __restrict__ w,
                                               int* cnt, float* sumw, int E) {
    int e = blockIdx.x * blockDim.x + threadIdx.x;
    if (e < E) {
        int d = dst[e];
        atomicAdd(&cnt[d], 1);
        atomicAdd(&sumw[d], w[e]);
    }
}

// scan + nodeprep fused (single block)
__global__ __launch_bounds__(1024) void k_scan(const int* __restrict__ cnt,
                                               const float* __restrict__ sumw,
                                               int* __restrict__ rowptr,
                                               float* __restrict__ dinv,
                                               float* __restrict__ lattr, int n) {
    __shared__ int sd[1024];
    int t = threadIdx.x;
    int chunk = (n + 1023) >> 10;
    int beg = min(t * chunk, n), end = min(beg + chunk, n);
    int s = 0;
    for (int i = beg; i < end; i++) s += cnt[i];
    sd[t] = s;
    __syncthreads();
    for (int off = 1; off < 1024; off <<= 1) {
        int v = (t >= off) ? sd[t - off] : 0;
        __syncthreads();
        sd[t] += v;
        __syncthreads();
    }
    int run = sd[t] - s;
    for (int i = beg; i < end; i++) {
        int c = cnt[i];
        rowptr[i] = run; run += c;
        float sw = sumw[i];
        dinv[i] = rsqrtf(sw + 1.f);            // deg >= 1 (self-loop)
        lattr[i] = (c > 0) ? sw / (float)c : 0.f;
    }
    if (t == 1023) rowptr[n] = sd[1023];
}

__global__ __launch_bounds__(256) void k_scatter(const int* __restrict__ src,
                                                 const int* __restrict__ dst,
                                                 const float* __restrict__ w,
                                                 const float* __restrict__ dinv,
                                                 const int* __restrict__ rowptr,
                                                 int* fill, int* eSrc, float* eW,
                                                 float* eNorm, int E) {
    int e = blockIdx.x * blockDim.x + threadIdx.x;
    if (e < E) {
        int d = dst[e], s = src[e];
        int pos = rowptr[d] + atomicAdd(&fill[d], 1);
        float we = w[e];
        eSrc[pos] = s;
        eW[pos] = we;
        eNorm[pos] = dinv[s] * we;   // × dinv[dst] applied in k_gcn_agg
    }
}

// Y[r, col] = sum_k X[r,k]*W[col,k] (+B); f32 and bf16 outputs.
__global__ __launch_bounds__(256) void k_gemm64(const float* __restrict__ X,
                                                const float* __restrict__ W,
                                                float* __restrict__ Yf,
                                                ushort* __restrict__ Yb,
                                                int n) {
    const int lane = threadIdx.x & 63;
    const int wid = blockIdx.x * 4 + (threadIdx.x >> 6);
    const int nw = gridDim.x * 4;
    float wreg[64];
    const float* wrow = W + (size_t)lane * 64;
#pragma unroll
    for (int k = 0; k < 64; k++) wreg[k] = wrow[k];
    for (int r = wid; r < n; r += nw) {
        float xv = X[(size_t)r * 64 + lane];
        float acc0 = 0.f, acc1 = 0.f;
#pragma unroll
        for (int k = 0; k < 64; k += 2) {
            acc0 = fmaf(rlanef(xv, k), wreg[k], acc0);
            acc1 = fmaf(rlanef(xv, k + 1), wreg[k + 1], acc1);
        }
        float res = acc0 + acc1;
        Yf[(size_t)r * 64 + lane] = res;
        Yb[(size_t)r * 64 + lane] = f2bf(res);
    }
}

// Dual GEMM: YL/YR[r,col] = X[r,:]·WL/WR[col,:] + BL/BR, col = blockIdx.y*64+lane.
__global__ __launch_bounds__(256) void k_gemm_lr(const float* __restrict__ X,
                                                 const float* __restrict__ WL,
                                                 const float* __restrict__ BL,
                                                 const float* __restrict__ WR,
                                                 const float* __restrict__ BR,
                                                 ushort* __restrict__ YL,
                                                 ushort* __restrict__ YR, int n) {
    const int lane = threadIdx.x & 63;
    const int col = blockIdx.y * 64 + lane;
    const int wid = blockIdx.x * 4 + (threadIdx.x >> 6);
    const int nw = gridDim.x * 4;
    float wl[64], wr[64];
    const float* wlrow = WL + (size_t)col * 64;
    const float* wrrow = WR + (size_t)col * 64;
#pragma unroll
    for (int k = 0; k < 64; k++) { wl[k] = wlrow[k]; wr[k] = wrrow[k]; }
    const float blv = BL[col], brv = BR[col];
    for (int r = wid; r < n; r += nw) {
        float xv = X[(size_t)r * 64 + lane];
        float aL0 = blv, aL1 = 0.f, aR0 = brv, aR1 = 0.f;
#pragma unroll
        for (int k = 0; k < 64; k += 2) {
            float x0 = rlanef(xv, k), x1 = rlanef(xv, k + 1);
            aL0 = fmaf(x0, wl[k], aL0);
            aL1 = fmaf(x1, wl[k + 1], aL1);
            aR0 = fmaf(x0, wr[k], aR0);
            aR1 = fmaf(x1, wr[k + 1], aR1);
        }
        YL[(size_t)r * 128 + col] = f2bf(aL0 + aL1);
        YR[(size_t)r * 128 + col] = f2bf(aR0 + aR1);
    }
}

// GCN aggregate: wave per node, 8-lane group per edge (8 ch/lane), 32 edges in flight.
__global__ __launch_bounds__(256) void k_gcn_agg(const float* __restrict__ h,
                                                 const uint* __restrict__ hbu,
                                                 const int* __restrict__ rowptr,
                                                 const int* __restrict__ eSrc,
                                                 const float* __restrict__ eNorm,
                                                 const float* __restrict__ dinv,
                                                 const float* __restrict__ b1,
                                                 float* __restrict__ hgcn, int nN) {
    const int lane = threadIdx.x & 63;
    const int node = blockIdx.x * 4 + (threadIdx.x >> 6);
    if (node >= nN) return;
    const int g = lane >> 3, sub = lane & 7;
    const float di = dinv[node];
    const char* hB = (const char*)hbu;
    const uint so = (uint)sub * 16u;
    float acc[8] = {0.f, 0.f, 0.f, 0.f, 0.f, 0.f, 0.f, 0.f};
    const int beg = rowptr[node], end = rowptr[node + 1];
    for (int base = beg; base < end; base += 32) {
        int e0 = base + g, e1 = e0 + 8, e2 = e0 + 16, e3 = e0 + 24;
        bool v0 = e0 < end, v1 = e1 < end, v2 = e2 < end, v3 = e3 < end;
        int s0 = v0 ? eSrc[e0] : node;
        int s1 = v1 ? eSrc[e1] : node;
        int s2 = v2 ? eSrc[e2] : node;
        int s3 = v3 ? eSrc[e3] : node;
        float n0 = v0 ? eNorm[e0] * di : 0.f;
        float n1 = v1 ? eNorm[e1] * di : 0.f;
        float n2 = v2 ? eNorm[e2] * di : 0.f;
        float n3 = v3 ? eNorm[e3] * di : 0.f;
        uint4 u0 = *(const uint4*)(hB + (((uint)s0) << 7) + so);
        uint4 u1 = *(const uint4*)(hB + (((uint)s1) << 7) + so);
        uint4 u2 = *(const uint4*)(hB + (((uint)s2) << 7) + so);
        uint4 u3 = *(const uint4*)(hB + (((uint)s3) << 7) + so);
        float xa[8], xb[8], xc[8], xd[8];
        unp8(u0, xa); unp8(u1, xb); unp8(u2, xc); unp8(u3, xd);
#pragma unroll
        for (int j = 0; j < 8; j++)
            acc[j] = fmaf(n0, xa[j], fmaf(n1, xb[j], fmaf(n2, xc[j], fmaf(n3, xd[j], acc[j]))));
    }
#pragma unroll
    for (int j = 0; j < 8; j++) {
        acc[j] += __shfl_xor(acc[j], 8, 64);
        acc[j] += __shfl_xor(acc[j], 16, 64);
        acc[j] += __shfl_xor(acc[j], 32, 64);
    }
    if (g == 0) {
        const int c0 = sub * 8;
        const float* hrow = h + (size_t)node * 64 + c0;
        float4 h1 = *(const float4*)hrow;
        float4 h2 = *(const float4*)(hrow + 4);
        float4 ba = *(const float4*)(b1 + c0);
        float4 bb = *(const float4*)(b1 + c0 + 4);
        float di2 = di * di;
        float4 o1, o2;
        o1.x = fmaxf(fmaf(di2, h1.x, acc[0]) + ba.x, 0.f);
        o1.y = fmaxf(fmaf(di2, h1.y, acc[1]) + ba.y, 0.f);
        o1.z = fmaxf(fmaf(di2, h1.z, acc[2]) + ba.z, 0.f);
        o1.w = fmaxf(fmaf(di2, h1.w, acc[3]) + ba.w, 0.f);
        o2.x = fmaxf(fmaf(di2, h2.x, acc[4]) + bb.x, 0.f);
        o2.y = fmaxf(fmaf(di2, h2.y, acc[5]) + bb.y, 0.f);
        o2.z = fmaxf(fmaf(di2, h2.z, acc[6]) + bb.z, 0.f);
        o2.w = fmaxf(fmaf(di2, h2.w, acc[7]) + bb.w, 0.f);
        float* orow = hgcn + (size_t)node * 64 + c0;
        *(float4*)orow = o1;
        *(float4*)(orow + 4) = o2;
    }
}

// Fused GATv2: wave per node, 16-lane group per edge (8 ch/lane, head = sub>>2),
// 16 edges in flight (4x unroll). alpha + softmax + PV + head-mean + skip, one pass.
__global__ __launch_bounds__(256) void k_gat_fused(const uint* __restrict__ XL,
                                                   const uint* __restrict__ XR,
                                                   const int* __restrict__ rowptr,
                                                   const int* __restrict__ eSrc,
                                                   const float* __restrict__ eW,
                                                   const float* __restrict__ lattr,
                                                   const float* __restrict__ We,
                                                   const float* __restrict__ att,
                                                   const float* __restrict__ bias_gat,
                                                   const float* __restrict__ x,
                                                   const float* __restrict__ Ws,
                                                   const float* __restrict__ bs,
                                                   const float* __restrict__ sgp,
                                                   float* __restrict__ out, int nN) {
    __shared__ float lds[4 * 608];
    const int lane = threadIdx.x & 63;
    const int wv = threadIdx.x >> 6;
    float* L = lds + wv * 608;
    const int g = lane >> 4, sub = lane & 15;
    const int hh = sub >> 2;
    const int c0 = sub * 8;
    const int node = blockIdx.x * 4 + wv;
    if (node >= nN) return;

    float We8[8], att8[8];
#pragma unroll
    for (int j = 0; j < 8; j++) { We8[j] = We[c0 + j]; att8[j] = att[c0 + j]; }

    const char* XLb = (const char*)XL;
    const uint so = (uint)sub * 16u;
    uint4 ur = *(const uint4*)((const char*)XR + (((uint)node) << 8) + so);
    float xr8[8];
    unp8(ur, xr8);

    float acc[8] = {0.f, 0.f, 0.f, 0.f, 0.f, 0.f, 0.f, 0.f};
    float den = 0.f;
    const int beg = rowptr[node], end = rowptr[node + 1];
    for (int base = beg; base < end; base += 16) {
        int e0 = base + g, e1 = e0 + 4, e2 = e0 + 8, e3 = e0 + 12;
        bool v0 = e0 < end, v1 = e1 < end, v2 = e2 < end, v3 = e3 < end;
        int s0 = v0 ? eSrc[e0] : node;
        int s1 = v1 ? eSrc[e1] : node;
        int s2 = v2 ? eSrc[e2] : node;
        int s3 = v3 ? eSrc[e3] : node;
        float w0 = v0 ? eW[e0] : 0.f;
        float w1 = v1 ? eW[e1] : 0.f;
        float w2 = v2 ? eW[e2] : 0.f;
        float w3 = v3 ? eW[e3] : 0.f;
        uint4 u0 = *(const uint4*)(XLb + (((uint)s0) << 8) + so);
        uint4 u1 = *(const uint4*)(XLb + (((uint)s1) << 8) + so);
        uint4 u2 = *(const uint4*)(XLb + (((uint)s2) << 8) + so);
        uint4 u3 = *(const uint4*)(XLb + (((uint)s3) << 8) + so);
        float xa[8], xb[8], xc[8], xd[8];
        unp8(u0, xa); unp8(u1, xb); unp8(u2, xc); unp8(u3, xd);
        float t0 = 0.f, t1 = 0.f, t2 = 0.f, t3 = 0.f;
#pragma unroll
        for (int j = 0; j < 8; j++) {
            float s = xr8[j], aj = att8[j], wj = We8[j];
            t0 = fmaf(lrelu(fmaf(w0, wj, xa[j] + s)), aj, t0);
            t1 = fmaf(lrelu(fmaf(w1, wj, xb[j] + s)), aj, t1);
            t2 = fmaf(lrelu(fmaf(w2, wj, xc[j] + s)), aj, t2);
            t3 = fmaf(lrelu(fmaf(w3, wj, xd[j] + s)), aj, t3);
        }
        t0 = red4(t0); t1 = red4(t1); t2 = red4(t2); t3 = red4(t3);
        float ex0 = v0 ? __expf(t0) : 0.f;
        float ex1 = v1 ? __expf(t1) : 0.f;
        float ex2 = v2 ? __expf(t2) : 0.f;
        float ex3 = v3 ? __expf(t3) : 0.f;
        den += (ex0 + ex1) + (ex2 + ex3);
#pragma unroll
        for (int j = 0; j < 8; j++)
            acc[j] = fmaf(ex0, xa[j], fmaf(ex1, xb[j], fmaf(ex2, xc[j], fmaf(ex3, xd[j], acc[j]))));
    }

    // self-loop alpha (identical across groups)
    float la = lattr[node];
    uint4 un = *(const uint4*)(XLb + (((uint)node) << 8) + so);
    float xn[8];
    unp8(un, xn);
    float ts = 0.f;
#pragma unroll
    for (int j = 0; j < 8; j++)
        ts = fmaf(lrelu(fmaf(la, We8[j], xn[j] + xr8[j])), att8[j], ts);
    ts = red4(ts);
    float es = __expf(ts);

    // stash partials in wave-private LDS (stride 9 -> conflict-free)
#pragma unroll
    for (int j = 0; j < 8; j++) L[lane * 9 + j] = acc[j];
    if ((sub & 3) == 0) L[576 + g * 4 + hh] = den;
    if (g == 0 && (sub & 3) == 0) L[592 + hh] = es;

    // epilogue: head-mean + self-loop + skip
    const int cs = lane & 31, h0 = lane >> 5;
    const ushort* XLus = (const ushort*)XL;
    float th = 0.f;
#pragma unroll
    for (int hd = 0; hd < 4; hd++) {
        int bl = hd * 4 + (cs >> 3);
        int j = cs & 7;
        float a = L[bl * 9 + j] + L[(16 + bl) * 9 + j] +
                  L[(32 + bl) * 9 + j] + L[(48 + bl) * 9 + j];
        float dn = L[576 + hd] + L[580 + hd] + L[584 + hd] + L[588 + hd];
        float eh = L[592 + hd];
        float xc = bfu(XLus[(size_t)node * 128 + hd * 32 + cs]);
        th += (a + eh * xc) / (dn + eh + 1e-16f);
    }
    const float4* xp = (const float4*)(x + (size_t)node * 64 + h0 * 32);
    const float4* wp = (const float4*)(Ws + (size_t)cs * 64 + h0 * 32);
    float sk = 0.f;
#pragma unroll
    for (int q = 0; q < 8; q++) {
        float4 xq = xp[q], wq = wp[q];
        sk += xq.x * wq.x + xq.y * wq.y + xq.z * wq.z + xq.w * wq.w;
    }
    sk += __shfl_xor(sk, 32, 64);
    float res = th * 0.25f + bias_gat[cs] + sgp[0] * (sk + bs[cs]);
    if (lane < 32) out[(size_t)node * 32 + cs] = res;
}

// ---------- launch ----------
extern "C" void kernel_launch(void* const* d_in, const int* in_sizes, int n_in,
                              void* d_out, int out_size, void* d_ws, size_t ws_size,
                              hipStream_t stream) {
    const float* x        = (const float*)d_in[0];
    const int*   ei       = (const int*)d_in[1];
    const float* ew       = (const float*)d_in[2];
    const float* W1       = (const float*)d_in[3];
    const float* b1       = (const float*)d_in[4];
    const float* Wl       = (const float*)d_in[5];
    const float* bl       = (const float*)d_in[6];
    const float* Wr       = (const float*)d_in[7];
    const float* br       = (const float*)d_in[8];
    const float* We       = (const float*)d_in[9];
    const float* att      = (const float*)d_in[10];
    const float* bias_gat = (const float*)d_in[11];
    const float* Ws       = (const float*)d_in[12];
    const float* bs       = (const float*)d_in[13];
    const float* sg       = (const float*)d_in[14];

    const int N = in_sizes[0] / 64;
    const int E = in_sizes[2];
    const int* srcI = ei;
    const int* dstI = ei + E;

    char* p = (char*)d_ws;
    auto alloc = [&](size_t bytes) {
        void* r = (void*)p;
        p += (bytes + 255) & ~(size_t)255;
        return r;
    };
    int*    cnt    = (int*)alloc((size_t)N * 4);
    int*    fill   = (int*)alloc((size_t)N * 4);
    int*    rowptr = (int*)alloc((size_t)(N + 1) * 4);
    int*    eSrc   = (int*)alloc((size_t)E * 4);
    float*  sumw   = (float*)alloc((size_t)N * 4);
    float*  dinv   = (float*)alloc((size_t)N * 4);
    float*  lattr  = (float*)alloc((size_t)N * 4);
    float*  eWc    = (float*)alloc((size_t)E * 4);
    float*  eNorm  = (float*)alloc((size_t)E * 4);
    float*  h      = (float*)alloc((size_t)N * 64 * 4);
    ushort* hb     = (ushort*)alloc((size_t)N * 64 * 2);
    float*  hgcn   = (float*)alloc((size_t)N * 64 * 4);
    ushort* xl_bf  = (ushort*)alloc((size_t)N * 128 * 2);
    ushort* xr_bf  = (ushort*)alloc((size_t)N * 128 * 2);
    if ((size_t)(p - (char*)d_ws) > ws_size) return;

    k_zero<<<(N + 255) / 256, 256, 0, stream>>>(cnt, sumw, fill, N);
    k_count<<<(E + 255) / 256, 256, 0, stream>>>(dstI, ew, cnt, sumw, E);
    k_scan<<<1, 1024, 0, stream>>>(cnt, sumw, rowptr, dinv, lattr, N);
    k_scatter<<<(E + 255) / 256, 256, 0, stream>>>(srcI, dstI, ew, dinv, rowptr,
                                                   fill, eSrc, eWc, eNorm, E);
    k_gemm64<<<1024, 256, 0, stream>>>(x, W1, h, hb, N);
    k_gcn_agg<<<(N + 3) / 4, 256, 0, stream>>>(h, (const uint*)hb, rowptr, eSrc,
                                               eNorm, dinv, b1, hgcn, N);
    k_gemm_lr<<<dim3(512, 2), 256, 0, stream>>>(hgcn, Wl, bl, Wr, br,
                                                xl_bf, xr_bf, N);
    k_gat_fused<<<(N + 3) / 4, 256, 0, stream>>>((const uint*)xl_bf, (const uint*)xr_bf,
                                                 rowptr, eSrc, eWc, lattr, We, att,
                                                 bias_gat, x, Ws, bs, sg,
                                                 (float*)d_out, N);
}

// Round 6
// 325.239 us; speedup vs baseline: 1.5552x; 1.5552x over previous
//
#include <hip/hip_runtime.h>
#include <hip/hip_bf16.h>

typedef unsigned int uint;
typedef unsigned short ushort;

// ---------- helpers ----------
__device__ __forceinline__ float bflo(uint u) { return __uint_as_float(u << 16); }
__device__ __forceinline__ float bfhi(uint u) { return __uint_as_float(u & 0xffff0000u); }
__device__ __forceinline__ float bfu(ushort s) { return __uint_as_float(((uint)s) << 16); }
__device__ __forceinline__ ushort f2bf(float f) {
    uint u = __float_as_uint(f);
    u += 0x7fffu + ((u >> 16) & 1u);   // RNE
    return (ushort)(u >> 16);
}
__device__ __forceinline__ float rlanef(float v, int j) {
    return __int_as_float(__builtin_amdgcn_readlane(__float_as_int(v), j));
}
// sum across 4-lane subgroup (lanes differing in bits 0,1)
__device__ __forceinline__ float red4(float v) {
    v += __shfl_xor(v, 1, 64);
    v += __shfl_xor(v, 2, 64);
    return v;
}
__device__ __forceinline__ float lrelu(float v) { return (v > 0.f) ? v : 0.2f * v; }
__device__ __forceinline__ void unp8(uint4 u, float* f) {
    f[0] = bflo(u.x); f[1] = bfhi(u.x);
    f[2] = bflo(u.y); f[3] = bfhi(u.y);
    f[4] = bflo(u.z); f[5] = bfhi(u.z);
    f[6] = bflo(u.w); f[7] = bfhi(u.w);
}

// ---------- build kernels ----------
__global__ __launch_bounds__(256) void k_zero(int* cnt, float* sumw, int* fill, int n) {
    int i = blockIdx.x * blockDim.x + threadIdx.x;
    if (i < n) { cnt[i] = 0; sumw[i] = 0.f; fill[i] = 0; }
}

__global__ __launch_bounds__(256) void k_count(const int* __restrict__ dst,
                                               const float* __restrict__ w,
                                               int* cnt, float* sumw, int E) {
    int e = blockIdx.x * blockDim.x + threadIdx.x;
    if (e < E) {
        int d = dst[e];
        atomicAdd(&cnt[d], 1);
        atomicAdd(&sumw[d], w[e]);
    }
}

// scan phase 1: per-block (256-element) sums of cnt
__global__ __launch_bounds__(256) void k_bsum(const int* __restrict__ cnt,
                                              int* __restrict__ bsum, int n) {
    const int i = blockIdx.x * 256 + threadIdx.x;
    const int lane = threadIdx.x & 63;
    int v = (i < n) ? cnt[i] : 0;
    v += __shfl_xor(v, 1, 64);
    v += __shfl_xor(v, 2, 64);
    v += __shfl_xor(v, 4, 64);
    v += __shfl_xor(v, 8, 64);
    v += __shfl_xor(v, 16, 64);
    v += __shfl_xor(v, 32, 64);
    __shared__ int ws[4];
    if (lane == 0) ws[threadIdx.x >> 6] = v;
    __syncthreads();
    if (threadIdx.x == 0)
        bsum[blockIdx.x] = ws[0] + ws[1] + ws[2] + ws[3];
}

// scan phase 2: single block, exclusive scan of block sums (nblk <= 1024)
__global__ __launch_bounds__(1024) void k_bscan(int* __restrict__ bsum,
                                                int* __restrict__ rowptrN, int nblk) {
    __shared__ int sd[1024];
    const int t = threadIdx.x;
    int v = (t < nblk) ? bsum[t] : 0;
    sd[t] = v;
    __syncthreads();
    for (int off = 1; off < 1024; off <<= 1) {
        int u = (t >= off) ? sd[t - off] : 0;
        __syncthreads();
        sd[t] += u;
        __syncthreads();
    }
    if (t < nblk) bsum[t] = sd[t] - v;      // exclusive prefix
    if (t == 1023) *rowptrN = sd[1023];     // total
}

// scan phase 3: in-block exclusive scan + block offset -> rowptr; nodeprep fused.
__global__ __launch_bounds__(256) void k_rowptr(const int* __restrict__ cnt,
                                                const int* __restrict__ bsum,
                                                const float* __restrict__ sumw,
                                                int* __restrict__ rowptr,
                                                float* __restrict__ dinv,
                                                float* __restrict__ lattr, int n) {
    __shared__ int sd[256];
    const int t = threadIdx.x;
    const int i = blockIdx.x * 256 + t;
    int c = (i < n) ? cnt[i] : 0;
    sd[t] = c;
    __syncthreads();
    for (int off = 1; off < 256; off <<= 1) {
        int u = (t >= off) ? sd[t - off] : 0;
        __syncthreads();
        sd[t] += u;
        __syncthreads();
    }
    if (i < n) {
        rowptr[i] = bsum[blockIdx.x] + sd[t] - c;
        float sw = sumw[i];
        dinv[i] = rsqrtf(sw + 1.f);                     // deg >= 1 (self-loop)
        lattr[i] = (c > 0) ? sw / (float)c : 0.f;
    }
}

__global__ __launch_bounds__(256) void k_scatter(const int* __restrict__ src,
                                                 const int* __restrict__ dst,
                                                 const float* __restrict__ w,
                                                 const float* __restrict__ dinv,
                                                 const int* __restrict__ rowptr,
                                                 int* fill, int* eSrc, float* eW,
                                                 float* eNorm, int E) {
    int e = blockIdx.x * blockDim.x + threadIdx.x;
    if (e < E) {
        int d = dst[e], s = src[e];
        int pos = rowptr[d] + atomicAdd(&fill[d], 1);
        float we = w[e];
        eSrc[pos] = s;
        eW[pos] = we;
        eNorm[pos] = dinv[s] * we;   // × dinv[dst] applied in k_gcn_agg
    }
}

// Y[r, col] = sum_k X[r,k]*W[col,k]; f32 and bf16 outputs.
__global__ __launch_bounds__(256) void k_gemm64(const float* __restrict__ X,
                                                const float* __restrict__ W,
                                                float* __restrict__ Yf,
                                                ushort* __restrict__ Yb,
                                                int n) {
    const int lane = threadIdx.x & 63;
    const int wid = blockIdx.x * 4 + (threadIdx.x >> 6);
    const int nw = gridDim.x * 4;
    float wreg[64];
    const float* wrow = W + (size_t)lane * 64;
#pragma unroll
    for (int k = 0; k < 64; k++) wreg[k] = wrow[k];
    for (int r = wid; r < n; r += nw) {
        float xv = X[(size_t)r * 64 + lane];
        float acc0 = 0.f, acc1 = 0.f;
#pragma unroll
        for (int k = 0; k < 64; k += 2) {
            acc0 = fmaf(rlanef(xv, k), wreg[k], acc0);
            acc1 = fmaf(rlanef(xv, k + 1), wreg[k + 1], acc1);
        }
        float res = acc0 + acc1;
        Yf[(size_t)r * 64 + lane] = res;
        Yb[(size_t)r * 64 + lane] = f2bf(res);
    }
}

// Dual GEMM: YL/YR[r,col] = X[r,:]·WL/WR[col,:] + BL/BR, col = blockIdx.y*64+lane.
__global__ __launch_bounds__(256) void k_gemm_lr(const float* __restrict__ X,
                                                 const float* __restrict__ WL,
                                                 const float* __restrict__ BL,
                                                 const float* __restrict__ WR,
                                                 const float* __restrict__ BR,
                                                 ushort* __restrict__ YL,
                                                 ushort* __restrict__ YR, int n) {
    const int lane = threadIdx.x & 63;
    const int col = blockIdx.y * 64 + lane;
    const int wid = blockIdx.x * 4 + (threadIdx.x >> 6);
    const int nw = gridDim.x * 4;
    float wl[64], wr[64];
    const float* wlrow = WL + (size_t)col * 64;
    const float* wrrow = WR + (size_t)col * 64;
#pragma unroll
    for (int k = 0; k < 64; k++) { wl[k] = wlrow[k]; wr[k] = wrrow[k]; }
    const float blv = BL[col], brv = BR[col];
    for (int r = wid; r < n; r += nw) {
        float xv = X[(size_t)r * 64 + lane];
        float aL0 = blv, aL1 = 0.f, aR0 = brv, aR1 = 0.f;
#pragma unroll
        for (int k = 0; k < 64; k += 2) {
            float x0 = rlanef(xv, k), x1 = rlanef(xv, k + 1);
            aL0 = fmaf(x0, wl[k], aL0);
            aL1 = fmaf(x1, wl[k + 1], aL1);
            aR0 = fmaf(x0, wr[k], aR0);
            aR1 = fmaf(x1, wr[k + 1], aR1);
        }
        YL[(size_t)r * 128 + col] = f2bf(aL0 + aL1);
        YR[(size_t)r * 128 + col] = f2bf(aR0 + aR1);
    }
}

// GCN aggregate: wave per node, 8-lane group per edge (8 ch/lane), 32 edges in flight.
__global__ __launch_bounds__(256) void k_gcn_agg(const float* __restrict__ h,
                                                 const uint* __restrict__ hbu,
                                                 const int* __restrict__ rowptr,
                                                 const int* __restrict__ eSrc,
                                                 const float* __restrict__ eNorm,
                                                 const float* __restrict__ dinv,
                                                 const float* __restrict__ b1,
                                                 float* __restrict__ hgcn, int nN) {
    const int lane = threadIdx.x & 63;
    const int node = blockIdx.x * 4 + (threadIdx.x >> 6);
    if (node >= nN) return;
    const int g = lane >> 3, sub = lane & 7;
    const float di = dinv[node];
    const char* hB = (const char*)hbu;
    const uint so = (uint)sub * 16u;
    float acc[8] = {0.f, 0.f, 0.f, 0.f, 0.f, 0.f, 0.f, 0.f};
    const int beg = rowptr[node], end = rowptr[node + 1];
    for (int base = beg; base < end; base += 32) {
        int e0 = base + g, e1 = e0 + 8, e2 = e0 + 16, e3 = e0 + 24;
        bool v0 = e0 < end, v1 = e1 < end, v2 = e2 < end, v3 = e3 < end;
        int s0 = v0 ? eSrc[e0] : node;
        int s1 = v1 ? eSrc[e1] : node;
        int s2 = v2 ? eSrc[e2] : node;
        int s3 = v3 ? eSrc[e3] : node;
        float n0 = v0 ? eNorm[e0] * di : 0.f;
        float n1 = v1 ? eNorm[e1] * di : 0.f;
        float n2 = v2 ? eNorm[e2] * di : 0.f;
        float n3 = v3 ? eNorm[e3] * di : 0.f;
        uint4 u0 = *(const uint4*)(hB + (((uint)s0) << 7) + so);
        uint4 u1 = *(const uint4*)(hB + (((uint)s1) << 7) + so);
        uint4 u2 = *(const uint4*)(hB + (((uint)s2) << 7) + so);
        uint4 u3 = *(const uint4*)(hB + (((uint)s3) << 7) + so);
        float xa[8], xb[8], xc[8], xd[8];
        unp8(u0, xa); unp8(u1, xb); unp8(u2, xc); unp8(u3, xd);
#pragma unroll
        for (int j = 0; j < 8; j++)
            acc[j] = fmaf(n0, xa[j], fmaf(n1, xb[j], fmaf(n2, xc[j], fmaf(n3, xd[j], acc[j]))));
    }
#pragma unroll
    for (int j = 0; j < 8; j++) {
        acc[j] += __shfl_xor(acc[j], 8, 64);
        acc[j] += __shfl_xor(acc[j], 16, 64);
        acc[j] += __shfl_xor(acc[j], 32, 64);
    }
    if (g == 0) {
        const int c0 = sub * 8;
        const float* hrow = h + (size_t)node * 64 + c0;
        float4 h1 = *(const float4*)hrow;
        float4 h2 = *(const float4*)(hrow + 4);
        float4 ba = *(const float4*)(b1 + c0);
        float4 bb = *(const float4*)(b1 + c0 + 4);
        float di2 = di * di;
        float4 o1, o2;
        o1.x = fmaxf(fmaf(di2, h1.x, acc[0]) + ba.x, 0.f);
        o1.y = fmaxf(fmaf(di2, h1.y, acc[1]) + ba.y, 0.f);
        o1.z = fmaxf(fmaf(di2, h1.z, acc[2]) + ba.z, 0.f);
        o1.w = fmaxf(fmaf(di2, h1.w, acc[3]) + ba.w, 0.f);
        o2.x = fmaxf(fmaf(di2, h2.x, acc[4]) + bb.x, 0.f);
        o2.y = fmaxf(fmaf(di2, h2.y, acc[5]) + bb.y, 0.f);
        o2.z = fmaxf(fmaf(di2, h2.z, acc[6]) + bb.z, 0.f);
        o2.w = fmaxf(fmaf(di2, h2.w, acc[7]) + bb.w, 0.f);
        float* orow = hgcn + (size_t)node * 64 + c0;
        *(float4*)orow = o1;
        *(float4*)(orow + 4) = o2;
    }
}

// Fused GATv2: wave per node, 16-lane group per edge (8 ch/lane, head = sub>>2),
// 16 edges in flight (4x unroll). alpha + softmax + PV + head-mean + skip, one pass.
__global__ __launch_bounds__(256) void k_gat_fused(const uint* __restrict__ XL,
                                                   const uint* __restrict__ XR,
                                                   const int* __restrict__ rowptr,
                                                   const int* __restrict__ eSrc,
                                                   const float* __restrict__ eW,
                                                   const float* __restrict__ lattr,
                                                   const float* __restrict__ We,
                                                   const float* __restrict__ att,
                                                   const float* __restrict__ bias_gat,
                                                   const float* __restrict__ x,
                                                   const float* __restrict__ Ws,
                                                   const float* __restrict__ bs,
                                                   const float* __restrict__ sgp,
                                                   float* __restrict__ out, int nN) {
    __shared__ float lds[4 * 608];
    const int lane = threadIdx.x & 63;
    const int wv = threadIdx.x >> 6;
    float* L = lds + wv * 608;
    const int g = lane >> 4, sub = lane & 15;
    const int hh = sub >> 2;
    const int c0 = sub * 8;
    const int node = blockIdx.x * 4 + wv;
    if (node >= nN) return;

    float We8[8], att8[8];
#pragma unroll
    for (int j = 0; j < 8; j++) { We8[j] = We[c0 + j]; att8[j] = att[c0 + j]; }

    const char* XLb = (const char*)XL;
    const uint so = (uint)sub * 16u;
    uint4 ur = *(const uint4*)((const char*)XR + (((uint)node) << 8) + so);
    float xr8[8];
    unp8(ur, xr8);

    float acc[8] = {0.f, 0.f, 0.f, 0.f, 0.f, 0.f, 0.f, 0.f};
    float den = 0.f;
    const int beg = rowptr[node], end = rowptr[node + 1];
    for (int base = beg; base < end; base += 16) {
        int e0 = base + g, e1 = e0 + 4, e2 = e0 + 8, e3 = e0 + 12;
        bool v0 = e0 < end, v1 = e1 < end, v2 = e2 < end, v3 = e3 < end;
        int s0 = v0 ? eSrc[e0] : node;
        int s1 = v1 ? eSrc[e1] : node;
        int s2 = v2 ? eSrc[e2] : node;
        int s3 = v3 ? eSrc[e3] : node;
        float w0 = v0 ? eW[e0] : 0.f;
        float w1 = v1 ? eW[e1] : 0.f;
        float w2 = v2 ? eW[e2] : 0.f;
        float w3 = v3 ? eW[e3] : 0.f;
        uint4 u0 = *(const uint4*)(XLb + (((uint)s0) << 8) + so);
        uint4 u1 = *(const uint4*)(XLb + (((uint)s1) << 8) + so);
        uint4 u2 = *(const uint4*)(XLb + (((uint)s2) << 8) + so);
        uint4 u3 = *(const uint4*)(XLb + (((uint)s3) << 8) + so);
        float xa[8], xb[8], xc[8], xd[8];
        unp8(u0, xa); unp8(u1, xb); unp8(u2, xc); unp8(u3, xd);
        float t0 = 0.f, t1 = 0.f, t2 = 0.f, t3 = 0.f;
#pragma unroll
        for (int j = 0; j < 8; j++) {
            float s = xr8[j], aj = att8[j], wj = We8[j];
            t0 = fmaf(lrelu(fmaf(w0, wj, xa[j] + s)), aj, t0);
            t1 = fmaf(lrelu(fmaf(w1, wj, xb[j] + s)), aj, t1);
            t2 = fmaf(lrelu(fmaf(w2, wj, xc[j] + s)), aj, t2);
            t3 = fmaf(lrelu(fmaf(w3, wj, xd[j] + s)), aj, t3);
        }
        t0 = red4(t0); t1 = red4(t1); t2 = red4(t2); t3 = red4(t3);
        float ex0 = v0 ? __expf(t0) : 0.f;
        float ex1 = v1 ? __expf(t1) : 0.f;
        float ex2 = v2 ? __expf(t2) : 0.f;
        float ex3 = v3 ? __expf(t3) : 0.f;
        den += (ex0 + ex1) + (ex2 + ex3);
#pragma unroll
        for (int j = 0; j < 8; j++)
            acc[j] = fmaf(ex0, xa[j], fmaf(ex1, xb[j], fmaf(ex2, xc[j], fmaf(ex3, xd[j], acc[j]))));
    }

    // self-loop alpha (identical across groups)
    float la = lattr[node];
    uint4 un = *(const uint4*)(XLb + (((uint)node) << 8) + so);
    float xn[8];
    unp8(un, xn);
    float ts = 0.f;
#pragma unroll
    for (int j = 0; j < 8; j++)
        ts = fmaf(lrelu(fmaf(la, We8[j], xn[j] + xr8[j])), att8[j], ts);
    ts = red4(ts);
    float es = __expf(ts);

    // stash partials in wave-private LDS (stride 9 -> conflict-free)
#pragma unroll
    for (int j = 0; j < 8; j++) L[lane * 9 + j] = acc[j];
    if ((sub & 3) == 0) L[576 + g * 4 + hh] = den;
    if (g == 0 && (sub & 3) == 0) L[592 + hh] = es;

    // epilogue: head-mean + self-loop + skip
    const int cs = lane & 31, h0 = lane >> 5;
    const ushort* XLus = (const ushort*)XL;
    float th = 0.f;
#pragma unroll
    for (int hd = 0; hd < 4; hd++) {
        int bl = hd * 4 + (cs >> 3);
        int j = cs & 7;
        float a = L[bl * 9 + j] + L[(16 + bl) * 9 + j] +
                  L[(32 + bl) * 9 + j] + L[(48 + bl) * 9 + j];
        float dn = L[576 + hd] + L[580 + hd] + L[584 + hd] + L[588 + hd];
        float eh = L[592 + hd];
        float xc = bfu(XLus[(size_t)node * 128 + hd * 32 + cs]);
        th += (a + eh * xc) / (dn + eh + 1e-16f);
    }
    const float4* xp = (const float4*)(x + (size_t)node * 64 + h0 * 32);
    const float4* wp = (const float4*)(Ws + (size_t)cs * 64 + h0 * 32);
    float sk = 0.f;
#pragma unroll
    for (int q = 0; q < 8; q++) {
        float4 xq = xp[q], wq = wp[q];
        sk += xq.x * wq.x + xq.y * wq.y + xq.z * wq.z + xq.w * wq.w;
    }
    sk += __shfl_xor(sk, 32, 64);
    float res = th * 0.25f + bias_gat[cs] + sgp[0] * (sk + bs[cs]);
    if (lane < 32) out[(size_t)node * 32 + cs] = res;
}

// ---------- launch ----------
extern "C" void kernel_launch(void* const* d_in, const int* in_sizes, int n_in,
                              void* d_out, int out_size, void* d_ws, size_t ws_size,
                              hipStream_t stream) {
    const float* x        = (const float*)d_in[0];
    const int*   ei       = (const int*)d_in[1];
    const float* ew       = (const float*)d_in[2];
    const float* W1       = (const float*)d_in[3];
    const float* b1       = (const float*)d_in[4];
    const float* Wl       = (const float*)d_in[5];
    const float* bl       = (const float*)d_in[6];
    const float* Wr       = (const float*)d_in[7];
    const float* br       = (const float*)d_in[8];
    const float* We       = (const float*)d_in[9];
    const float* att      = (const float*)d_in[10];
    const float* bias_gat = (const float*)d_in[11];
    const float* Ws       = (const float*)d_in[12];
    const float* bs       = (const float*)d_in[13];
    const float* sg       = (const float*)d_in[14];

    const int N = in_sizes[0] / 64;
    const int E = in_sizes[2];
    const int* srcI = ei;
    const int* dstI = ei + E;
    const int nblk = (N + 255) / 256;   // <= 1024 for N <= 262144

    char* p = (char*)d_ws;
    auto alloc = [&](size_t bytes) {
        void* r = (void*)p;
        p += (bytes + 255) & ~(size_t)255;
        return r;
    };
    int*    cnt    = (int*)alloc((size_t)N * 4);
    int*    fill   = (int*)alloc((size_t)N * 4);
    int*    rowptr = (int*)alloc((size_t)(N + 1) * 4);
    int*    bsum   = (int*)alloc((size_t)nblk * 4);
    int*    eSrc   = (int*)alloc((size_t)E * 4);
    float*  sumw   = (float*)alloc((size_t)N * 4);
    float*  dinv   = (float*)alloc((size_t)N * 4);
    float*  lattr  = (float*)alloc((size_t)N * 4);
    float*  eWc    = (float*)alloc((size_t)E * 4);
    float*  eNorm  = (float*)alloc((size_t)E * 4);
    float*  h      = (float*)alloc((size_t)N * 64 * 4);
    ushort* hb     = (ushort*)alloc((size_t)N * 64 * 2);
    float*  hgcn   = (float*)alloc((size_t)N * 64 * 4);
    ushort* xl_bf  = (ushort*)alloc((size_t)N * 128 * 2);
    ushort* xr_bf  = (ushort*)alloc((size_t)N * 128 * 2);
    if ((size_t)(p - (char*)d_ws) > ws_size) return;

    k_zero<<<(N + 255) / 256, 256, 0, stream>>>(cnt, sumw, fill, N);
    k_count<<<(E + 255) / 256, 256, 0, stream>>>(dstI, ew, cnt, sumw, E);
    k_bsum<<<nblk, 256, 0, stream>>>(cnt, bsum, N);
    k_bscan<<<1, 1024, 0, stream>>>(bsum, rowptr + N, nblk);
    k_rowptr<<<nblk, 256, 0, stream>>>(cnt, bsum, sumw, rowptr, dinv, lattr, N);
    k_scatter<<<(E + 255) / 256, 256, 0, stream>>>(srcI, dstI, ew, dinv, rowptr,
                                                   fill, eSrc, eWc, eNorm, E);
    k_gemm64<<<1024, 256, 0, stream>>>(x, W1, h, hb, N);
    k_gcn_agg<<<(N + 3) / 4, 256, 0, stream>>>(h, (const uint*)hb, rowptr, eSrc,
                                               eNorm, dinv, b1, hgcn, N);
    k_gemm_lr<<<dim3(512, 2), 256, 0, stream>>>(hgcn, Wl, bl, Wr, br,
                                                xl_bf, xr_bf, N);
    k_gat_fused<<<(N + 3) / 4, 256, 0, stream>>>((const uint*)xl_bf, (const uint*)xr_bf,
                                                 rowptr, eSrc, eWc, lattr, We, att,
                                                 bias_gat, x, Ws, bs, sg,
                                                 (float*)d_out, N);
}

// Round 7
// 305.128 us; speedup vs baseline: 1.6577x; 1.0659x over previous
//
#include <hip/hip_runtime.h>
#include <hip/hip_bf16.h>

typedef unsigned int uint;
typedef unsigned short ushort;
typedef __attribute__((ext_vector_type(8))) short short8v;
typedef __attribute__((ext_vector_type(4))) float f32x4;

// ---------- helpers ----------
__device__ __forceinline__ float bflo(uint u) { return __uint_as_float(u << 16); }
__device__ __forceinline__ float bfhi(uint u) { return __uint_as_float(u & 0xffff0000u); }
__device__ __forceinline__ float bfu(ushort s) { return __uint_as_float(((uint)s) << 16); }
__device__ __forceinline__ ushort f2bf(float f) {
    uint u = __float_as_uint(f);
    u += 0x7fffu + ((u >> 16) & 1u);   // RNE
    return (ushort)(u >> 16);
}
__device__ __forceinline__ uint pk2(float lo, float hi) {
    return (uint)f2bf(lo) | ((uint)f2bf(hi) << 16);
}
// sum across 4-lane subgroup
__device__ __forceinline__ float red4(float v) {
    v += __shfl_xor(v, 1, 64);
    v += __shfl_xor(v, 2, 64);
    return v;
}
__device__ __forceinline__ float lrelu(float v) { return (v > 0.f) ? v : 0.2f * v; }
__device__ __forceinline__ void unp8(uint4 u, float* f) {
    f[0] = bflo(u.x); f[1] = bfhi(u.x);
    f[2] = bflo(u.y); f[3] = bfhi(u.y);
    f[4] = bflo(u.z); f[5] = bfhi(u.z);
    f[6] = bflo(u.w); f[7] = bfhi(u.w);
}

// ---------- build kernels ----------
__global__ __launch_bounds__(256) void k_zero(int* cnt, float* sumw, int* fill, int n) {
    int i = blockIdx.x * blockDim.x + threadIdx.x;
    if (i < n) { cnt[i] = 0; sumw[i] = 0.f; fill[i] = 0; }
}

__global__ __launch_bounds__(256) void k_count(const int* __restrict__ dst,
                                               const float* __restrict__ w,
                                               int* cnt, float* sumw, int E) {
    int e = blockIdx.x * blockDim.x + threadIdx.x;
    if (e < E) {
        int d = dst[e];
        atomicAdd(&cnt[d], 1);
        atomicAdd(&sumw[d], w[e]);
    }
}

__global__ __launch_bounds__(256) void k_bsum(const int* __restrict__ cnt,
                                              int* __restrict__ bsum, int n) {
    const int i = blockIdx.x * 256 + threadIdx.x;
    const int lane = threadIdx.x & 63;
    int v = (i < n) ? cnt[i] : 0;
    v += __shfl_xor(v, 1, 64);
    v += __shfl_xor(v, 2, 64);
    v += __shfl_xor(v, 4, 64);
    v += __shfl_xor(v, 8, 64);
    v += __shfl_xor(v, 16, 64);
    v += __shfl_xor(v, 32, 64);
    __shared__ int ws[4];
    if (lane == 0) ws[threadIdx.x >> 6] = v;
    __syncthreads();
    if (threadIdx.x == 0)
        bsum[blockIdx.x] = ws[0] + ws[1] + ws[2] + ws[3];
}

__global__ __launch_bounds__(1024) void k_bscan(int* __restrict__ bsum,
                                                int* __restrict__ rowptrN, int nblk) {
    __shared__ int sd[1024];
    const int t = threadIdx.x;
    int v = (t < nblk) ? bsum[t] : 0;
    sd[t] = v;
    __syncthreads();
    for (int off = 1; off < 1024; off <<= 1) {
        int u = (t >= off) ? sd[t - off] : 0;
        __syncthreads();
        sd[t] += u;
        __syncthreads();
    }
    if (t < nblk) bsum[t] = sd[t] - v;
    if (t == 1023) *rowptrN = sd[1023];
}

__global__ __launch_bounds__(256) void k_rowptr(const int* __restrict__ cnt,
                                                const int* __restrict__ bsum,
                                                const float* __restrict__ sumw,
                                                int* __restrict__ rowptr,
                                                float* __restrict__ dinv,
                                                float* __restrict__ lattr, int n) {
    __shared__ int sd[256];
    const int t = threadIdx.x;
    const int i = blockIdx.x * 256 + t;
    int c = (i < n) ? cnt[i] : 0;
    sd[t] = c;
    __syncthreads();
    for (int off = 1; off < 256; off <<= 1) {
        int u = (t >= off) ? sd[t - off] : 0;
        __syncthreads();
        sd[t] += u;
        __syncthreads();
    }
    if (i < n) {
        rowptr[i] = bsum[blockIdx.x] + sd[t] - c;
        float sw = sumw[i];
        dinv[i] = rsqrtf(sw + 1.f);
        lattr[i] = (c > 0) ? sw / (float)c : 0.f;
    }
}

// scatter: eSW = {src, w bits} for GAT; eSN = {src, dinv[s]*w bits} for GCN.
__global__ __launch_bounds__(256) void k_scatter(const int* __restrict__ src,
                                                 const int* __restrict__ dst,
                                                 const float* __restrict__ w,
                                                 const float* __restrict__ dinv,
                                                 const int* __restrict__ rowptr,
                                                 int* fill, int2* eSW, int2* eSN, int E) {
    int e = blockIdx.x * blockDim.x + threadIdx.x;
    if (e < E) {
        int d = dst[e], s = src[e];
        int pos = rowptr[d] + atomicAdd(&fill[d], 1);
        float we = w[e];
        eSW[pos] = make_int2(s, __float_as_int(we));
        eSN[pos] = make_int2(s, __float_as_int(dinv[s] * we));
    }
}

// weight conversion f32 -> bf16 (W1: 4096, Wl/Wr: 8192 each)
__global__ __launch_bounds__(256) void k_cvtw(const float* __restrict__ W1,
                                              const float* __restrict__ Wl,
                                              const float* __restrict__ Wr,
                                              ushort* w1b, ushort* wlb, ushort* wrb) {
    int i = blockIdx.x * 256 + threadIdx.x;
    if (i < 4096) w1b[i] = f2bf(W1[i]);
    if (i < 8192) { wlb[i] = f2bf(Wl[i]); wrb[i] = f2bf(Wr[i]); }
}

// MFMA GEMM: hb[r,c] = x[r,:]·W1[c,:] (bf16 out). One wave per 16-row tile.
__global__ __launch_bounds__(256) void k_gemm_x(const float* __restrict__ X,
                                                const ushort* __restrict__ W1b,
                                                ushort* __restrict__ hb, int Mt) {
    const int wv = blockIdx.x * 4 + (threadIdx.x >> 6);
    if (wv >= Mt) return;
    const int lane = threadIdx.x & 63;
    const int r16 = lane & 15, kseg = lane >> 4;
    const float* xr = X + ((size_t)(wv * 16 + r16)) * 64 + kseg * 8;
    float4 x0 = *(const float4*)xr;
    float4 x1 = *(const float4*)(xr + 4);
    float4 x2 = *(const float4*)(xr + 32);
    float4 x3 = *(const float4*)(xr + 36);
    short8v a0, a1;
    a0[0] = (short)f2bf(x0.x); a0[1] = (short)f2bf(x0.y);
    a0[2] = (short)f2bf(x0.z); a0[3] = (short)f2bf(x0.w);
    a0[4] = (short)f2bf(x1.x); a0[5] = (short)f2bf(x1.y);
    a0[6] = (short)f2bf(x1.z); a0[7] = (short)f2bf(x1.w);
    a1[0] = (short)f2bf(x2.x); a1[1] = (short)f2bf(x2.y);
    a1[2] = (short)f2bf(x2.z); a1[3] = (short)f2bf(x2.w);
    a1[4] = (short)f2bf(x3.x); a1[5] = (short)f2bf(x3.y);
    a1[6] = (short)f2bf(x3.z); a1[7] = (short)f2bf(x3.w);
    const short8v* Wv = (const short8v*)W1b;
    f32x4 acc[4];
#pragma unroll
    for (int t = 0; t < 4; t++) acc[t] = (f32x4){0.f, 0.f, 0.f, 0.f};
#pragma unroll
    for (int t = 0; t < 4; t++) {
        int col = t * 16 + r16;
        acc[t] = __builtin_amdgcn_mfma_f32_16x16x32_bf16(a0, Wv[col * 8 + kseg], acc[t], 0, 0, 0);
        acc[t] = __builtin_amdgcn_mfma_f32_16x16x32_bf16(a1, Wv[col * 8 + 4 + kseg], acc[t], 0, 0, 0);
    }
#pragma unroll
    for (int t = 0; t < 4; t++)
#pragma unroll
        for (int i = 0; i < 4; i++)
            hb[((size_t)(wv * 16 + kseg * 4 + i)) * 64 + t * 16 + r16] = f2bf(acc[t][i]);
}

// MFMA dual GEMM: YL/YR[r,c] = A[r,:]·WL/WR[c,:] + BL/BR. A bf16 [M,64].
__global__ __launch_bounds__(256) void k_gemm_lr(const ushort* __restrict__ Ab,
                                                 const ushort* __restrict__ WLb,
                                                 const float* __restrict__ BL,
                                                 const ushort* __restrict__ WRb,
                                                 const float* __restrict__ BR,
                                                 ushort* __restrict__ YL,
                                                 ushort* __restrict__ YR, int Mt) {
    const int wv = blockIdx.x * 4 + (threadIdx.x >> 6);
    if (wv >= Mt) return;
    const int lane = threadIdx.x & 63;
    const int r16 = lane & 15, kseg = lane >> 4;
    const short8v* arow = (const short8v*)(Ab + ((size_t)(wv * 16 + r16)) * 64);
    short8v a0 = arow[kseg], a1 = arow[4 + kseg];
    const short8v* WvL = (const short8v*)WLb;
    const short8v* WvR = (const short8v*)WRb;
    f32x4 accL[8], accR[8];
#pragma unroll
    for (int t = 0; t < 8; t++) {
        accL[t] = (f32x4){0.f, 0.f, 0.f, 0.f};
        accR[t] = (f32x4){0.f, 0.f, 0.f, 0.f};
    }
#pragma unroll
    for (int t = 0; t < 8; t++) {
        int col = t * 16 + r16;
        accL[t] = __builtin_amdgcn_mfma_f32_16x16x32_bf16(a0, WvL[col * 8 + kseg], accL[t], 0, 0, 0);
        accL[t] = __builtin_amdgcn_mfma_f32_16x16x32_bf16(a1, WvL[col * 8 + 4 + kseg], accL[t], 0, 0, 0);
        accR[t] = __builtin_amdgcn_mfma_f32_16x16x32_bf16(a0, WvR[col * 8 + kseg], accR[t], 0, 0, 0);
        accR[t] = __builtin_amdgcn_mfma_f32_16x16x32_bf16(a1, WvR[col * 8 + 4 + kseg], accR[t], 0, 0, 0);
    }
#pragma unroll
    for (int t = 0; t < 8; t++) {
        int col = t * 16 + r16;
        float blv = BL[col], brv = BR[col];
#pragma unroll
        for (int i = 0; i < 4; i++) {
            size_t row = (size_t)(wv * 16 + kseg * 4 + i);
            YL[row * 128 + col] = f2bf(accL[t][i] + blv);
            YR[row * 128 + col] = f2bf(accR[t][i] + brv);
        }
    }
}

// GCN aggregate: wave per node, 8-lane group per edge (8 ch/lane), 16 edges in flight.
__global__ __launch_bounds__(256) void k_gcn_agg(const ushort* __restrict__ hb,
                                                 const int* __restrict__ rowptr,
                                                 const int2* __restrict__ eSN,
                                                 const float* __restrict__ dinv,
                                                 const float* __restrict__ b1,
                                                 ushort* __restrict__ hgb, int nN) {
    const int lane = threadIdx.x & 63;
    const int node = blockIdx.x * 4 + (threadIdx.x >> 6);
    if (node >= nN) return;
    const int g = lane >> 3, sub = lane & 7;
    const float di = dinv[node];
    const char* hB = (const char*)hb;
    const uint so = (uint)sub * 16u;
    float acc[8] = {0.f, 0.f, 0.f, 0.f, 0.f, 0.f, 0.f, 0.f};
    const int beg = rowptr[node], end = rowptr[node + 1];
    for (int base = beg; base < end; base += 16) {
        int e0 = base + g, e1 = e0 + 8;
        bool v0 = e0 < end, v1 = e1 < end;
        int2 q0 = v0 ? eSN[e0] : make_int2(node, 0);
        int2 q1 = v1 ? eSN[e1] : make_int2(node, 0);
        float n0 = __int_as_float(q0.y) * di;
        float n1 = __int_as_float(q1.y) * di;
        uint4 u0 = *(const uint4*)(hB + (((uint)q0.x) << 7) + so);
        uint4 u1 = *(const uint4*)(hB + (((uint)q1.x) << 7) + so);
        float xa[8], xb[8];
        unp8(u0, xa); unp8(u1, xb);
#pragma unroll
        for (int j = 0; j < 8; j++)
            acc[j] = fmaf(n0, xa[j], fmaf(n1, xb[j], acc[j]));
    }
#pragma unroll
    for (int j = 0; j < 8; j++) {
        acc[j] += __shfl_xor(acc[j], 8, 64);
        acc[j] += __shfl_xor(acc[j], 16, 64);
        acc[j] += __shfl_xor(acc[j], 32, 64);
    }
    if (g == 0) {
        const int c0 = sub * 8;
        uint4 hv = *(const uint4*)(hB + (((uint)node) << 7) + so);
        float h8[8];
        unp8(hv, h8);
        float4 ba = *(const float4*)(b1 + c0);
        float4 bb = *(const float4*)(b1 + c0 + 4);
        float di2 = di * di;
        float o[8];
        o[0] = fmaxf(fmaf(di2, h8[0], acc[0]) + ba.x, 0.f);
        o[1] = fmaxf(fmaf(di2, h8[1], acc[1]) + ba.y, 0.f);
        o[2] = fmaxf(fmaf(di2, h8[2], acc[2]) + ba.z, 0.f);
        o[3] = fmaxf(fmaf(di2, h8[3], acc[3]) + ba.w, 0.f);
        o[4] = fmaxf(fmaf(di2, h8[4], acc[4]) + bb.x, 0.f);
        o[5] = fmaxf(fmaf(di2, h8[5], acc[5]) + bb.y, 0.f);
        o[6] = fmaxf(fmaf(di2, h8[6], acc[6]) + bb.z, 0.f);
        o[7] = fmaxf(fmaf(di2, h8[7], acc[7]) + bb.w, 0.f);
        uint4 ov;
        ov.x = pk2(o[0], o[1]);
        ov.y = pk2(o[2], o[3]);
        ov.z = pk2(o[4], o[5]);
        ov.w = pk2(o[6], o[7]);
        *(uint4*)((char*)hgb + (((uint)node) << 7) + so) = ov;
    }
}

// Fused GATv2: wave per node, 16-lane group per edge (8 ch/lane, head = sub>>2),
// 8 edges in flight (2x unroll). alpha + softmax + PV + head-mean + skip, one pass.
__global__ __launch_bounds__(256) void k_gat_fused(const uint* __restrict__ XL,
                                                   const uint* __restrict__ XR,
                                                   const int* __restrict__ rowptr,
                                                   const int2* __restrict__ eSW,
                                                   const float* __restrict__ lattr,
                                                   const float* __restrict__ We,
                                                   const float* __restrict__ att,
                                                   const float* __restrict__ bias_gat,
                                                   const float* __restrict__ x,
                                                   const float* __restrict__ Ws,
                                                   const float* __restrict__ bs,
                                                   const float* __restrict__ sgp,
                                                   float* __restrict__ out, int nN) {
    __shared__ float lds[4 * 608];
    const int lane = threadIdx.x & 63;
    const int wv = threadIdx.x >> 6;
    float* L = lds + wv * 608;
    const int g = lane >> 4, sub = lane & 15;
    const int hh = sub >> 2;
    const int c0 = sub * 8;
    const int node = blockIdx.x * 4 + wv;
    if (node >= nN) return;

    float We8[8], att8[8];
#pragma unroll
    for (int j = 0; j < 8; j++) { We8[j] = We[c0 + j]; att8[j] = att[c0 + j]; }

    const char* XLb = (const char*)XL;
    const uint so = (uint)sub * 16u;
    uint4 ur = *(const uint4*)((const char*)XR + (((uint)node) << 8) + so);
    float xr8[8];
    unp8(ur, xr8);

    float acc[8] = {0.f, 0.f, 0.f, 0.f, 0.f, 0.f, 0.f, 0.f};
    float den = 0.f;
    const int beg = rowptr[node], end = rowptr[node + 1];
    for (int base = beg; base < end; base += 8) {
        int e0 = base + g, e1 = e0 + 4;
        bool v0 = e0 < end, v1 = e1 < end;
        int2 q0 = v0 ? eSW[e0] : make_int2(node, 0);
        int2 q1 = v1 ? eSW[e1] : make_int2(node, 0);
        float w0 = __int_as_float(q0.y), w1 = __int_as_float(q1.y);
        uint4 u0 = *(const uint4*)(XLb + (((uint)q0.x) << 8) + so);
        uint4 u1 = *(const uint4*)(XLb + (((uint)q1.x) << 8) + so);
        float xa[8], xb[8];
        unp8(u0, xa); unp8(u1, xb);
        float t0 = 0.f, t1 = 0.f;
#pragma unroll
        for (int j = 0; j < 8; j++) {
            float s = xr8[j], aj = att8[j], wj = We8[j];
            t0 = fmaf(lrelu(fmaf(w0, wj, xa[j] + s)), aj, t0);
            t1 = fmaf(lrelu(fmaf(w1, wj, xb[j] + s)), aj, t1);
        }
        t0 = red4(t0);
        t1 = red4(t1);
        float ex0 = v0 ? __expf(t0) : 0.f;
        float ex1 = v1 ? __expf(t1) : 0.f;
        den += ex0 + ex1;
#pragma unroll
        for (int j = 0; j < 8; j++)
            acc[j] = fmaf(ex0, xa[j], fmaf(ex1, xb[j], acc[j]));
    }

    // self-loop alpha (identical across groups)
    float la = lattr[node];
    uint4 un = *(const uint4*)(XLb + (((uint)node) << 8) + so);
    float xn[8];
    unp8(un, xn);
    float ts = 0.f;
#pragma unroll
    for (int j = 0; j < 8; j++)
        ts = fmaf(lrelu(fmaf(la, We8[j], xn[j] + xr8[j])), att8[j], ts);
    ts = red4(ts);
    float es = __expf(ts);

    // stash partials in wave-private LDS (stride 9)
#pragma unroll
    for (int j = 0; j < 8; j++) L[lane * 9 + j] = acc[j];
    if ((sub & 3) == 0) L[576 + g * 4 + hh] = den;
    if (g == 0 && (sub & 3) == 0) L[592 + hh] = es;

    // epilogue: head-mean + self-loop + skip
    const int cs = lane & 31, h0 = lane >> 5;
    const ushort* XLus = (const ushort*)XL;
    float th = 0.f;
#pragma unroll
    for (int hd = 0; hd < 4; hd++) {
        int bl = hd * 4 + (cs >> 3);
        int j = cs & 7;
        float a = L[bl * 9 + j] + L[(16 + bl) * 9 + j] +
                  L[(32 + bl) * 9 + j] + L[(48 + bl) * 9 + j];
        float dn = L[576 + hd] + L[580 + hd] + L[584 + hd] + L[588 + hd];
        float eh = L[592 + hd];
        float xc = bfu(XLus[(size_t)node * 128 + hd * 32 + cs]);
        th += (a + eh * xc) / (dn + eh + 1e-16f);
    }
    const float4* xp = (const float4*)(x + (size_t)node * 64 + h0 * 32);
    const float4* wp = (const float4*)(Ws + (size_t)cs * 64 + h0 * 32);
    float sk = 0.f;
#pragma unroll
    for (int q = 0; q < 8; q++) {
        float4 xq = xp[q], wq = wp[q];
        sk += xq.x * wq.x + xq.y * wq.y + xq.z * wq.z + xq.w * wq.w;
    }
    sk += __shfl_xor(sk, 32, 64);
    float res = th * 0.25f + bias_gat[cs] + sgp[0] * (sk + bs[cs]);
    if (lane < 32) out[(size_t)node * 32 + cs] = res;
}

// ---------- launch ----------
extern "C" void kernel_launch(void* const* d_in, const int* in_sizes, int n_in,
                              void* d_out, int out_size, void* d_ws, size_t ws_size,
                              hipStream_t stream) {
    const float* x        = (const float*)d_in[0];
    const int*   ei       = (const int*)d_in[1];
    const float* ew       = (const float*)d_in[2];
    const float* W1       = (const float*)d_in[3];
    const float* b1       = (const float*)d_in[4];
    const float* Wl       = (const float*)d_in[5];
    const float* bl       = (const float*)d_in[6];
    const float* Wr       = (const float*)d_in[7];
    const float* br       = (const float*)d_in[8];
    const float* We       = (const float*)d_in[9];
    const float* att      = (const float*)d_in[10];
    const float* bias_gat = (const float*)d_in[11];
    const float* Ws       = (const float*)d_in[12];
    const float* bs       = (const float*)d_in[13];
    const float* sg       = (const float*)d_in[14];

    const int N = in_sizes[0] / 64;
    const int E = in_sizes[2];
    const int* srcI = ei;
    const int* dstI = ei + E;
    const int nblk = (N + 255) / 256;
    const int Mt = (N + 15) / 16;        // 16-row GEMM tiles (N=50000 -> 3125)

    char* p = (char*)d_ws;
    auto alloc = [&](size_t bytes) {
        void* r = (void*)p;
        p += (bytes + 255) & ~(size_t)255;
        return r;
    };
    int*    cnt    = (int*)alloc((size_t)N * 4);
    int*    fill   = (int*)alloc((size_t)N * 4);
    int*    rowptr = (int*)alloc((size_t)(N + 1) * 4);
    int*    bsum   = (int*)alloc((size_t)nblk * 4);
    int2*   eSW    = (int2*)alloc((size_t)E * 8);
    int2*   eSN    = (int2*)alloc((size_t)E * 8);
    float*  sumw   = (float*)alloc((size_t)N * 4);
    float*  dinv   = (float*)alloc((size_t)N * 4);
    float*  lattr  = (float*)alloc((size_t)N * 4);
    ushort* hb     = (ushort*)alloc((size_t)Mt * 16 * 64 * 2);
    ushort* hgb    = (ushort*)alloc((size_t)Mt * 16 * 64 * 2);
    ushort* xl_bf  = (ushort*)alloc((size_t)Mt * 16 * 128 * 2);
    ushort* xr_bf  = (ushort*)alloc((size_t)Mt * 16 * 128 * 2);
    ushort* w1b    = (ushort*)alloc(4096 * 2);
    ushort* wlb    = (ushort*)alloc(8192 * 2);
    ushort* wrb    = (ushort*)alloc(8192 * 2);
    if ((size_t)(p - (char*)d_ws) > ws_size) return;

    k_zero<<<(N + 255) / 256, 256, 0, stream>>>(cnt, sumw, fill, N);
    k_count<<<(E + 255) / 256, 256, 0, stream>>>(dstI, ew, cnt, sumw, E);
    k_bsum<<<nblk, 256, 0, stream>>>(cnt, bsum, N);
    k_bscan<<<1, 1024, 0, stream>>>(bsum, rowptr + N, nblk);
    k_rowptr<<<nblk, 256, 0, stream>>>(cnt, bsum, sumw, rowptr, dinv, lattr, N);
    k_scatter<<<(E + 255) / 256, 256, 0, stream>>>(srcI, dstI, ew, dinv, rowptr,
                                                   fill, eSW, eSN, E);
    k_cvtw<<<32, 256, 0, stream>>>(W1, Wl, Wr, w1b, wlb, wrb);
    k_gemm_x<<<(Mt + 3) / 4, 256, 0, stream>>>(x, w1b, hb, Mt);
    k_gcn_agg<<<(N + 3) / 4, 256, 0, stream>>>(hb, rowptr, eSN, dinv, b1, hgb, N);
    k_gemm_lr<<<(Mt + 3) / 4, 256, 0, stream>>>(hgb, wlb, bl, wrb, br,
                                                xl_bf, xr_bf, Mt);
    k_gat_fused<<<(N + 3) / 4, 256, 0, stream>>>((const uint*)xl_bf, (const uint*)xr_bf,
                                                 rowptr, eSW, lattr, We, att,
                                                 bias_gat, x, Ws, bs, sg,
                                                 (float*)d_out, N);
}

// Round 8
// 282.002 us; speedup vs baseline: 1.7936x; 1.0820x over previous
//
#include <hip/hip_runtime.h>
#include <hip/hip_bf16.h>

typedef unsigned int uint;
typedef unsigned short ushort;
typedef __attribute__((ext_vector_type(8))) short short8v;
typedef __attribute__((ext_vector_type(4))) float f32x4;

// ---------- helpers ----------
__device__ __forceinline__ float bflo(uint u) { return __uint_as_float(u << 16); }
__device__ __forceinline__ float bfhi(uint u) { return __uint_as_float(u & 0xffff0000u); }
__device__ __forceinline__ float bfu(ushort s) { return __uint_as_float(((uint)s) << 16); }
__device__ __forceinline__ ushort f2bf(float f) {
    uint u = __float_as_uint(f);
    u += 0x7fffu + ((u >> 16) & 1u);   // RNE
    return (ushort)(u >> 16);
}
__device__ __forceinline__ uint pk2(float lo, float hi) {
    return (uint)f2bf(lo) | ((uint)f2bf(hi) << 16);
}
__device__ __forceinline__ float red4(float v) {
    v += __shfl_xor(v, 1, 64);
    v += __shfl_xor(v, 2, 64);
    return v;
}
__device__ __forceinline__ float lrelu(float v) { return (v > 0.f) ? v : 0.2f * v; }
__device__ __forceinline__ void unp8(uint4 u, float* f) {
    f[0] = bflo(u.x); f[1] = bfhi(u.x);
    f[2] = bflo(u.y); f[3] = bfhi(u.y);
    f[4] = bflo(u.z); f[5] = bfhi(u.z);
    f[6] = bflo(u.w); f[7] = bfhi(u.w);
}

// ---------- build kernels ----------
__global__ __launch_bounds__(256) void k_count(const int* __restrict__ dst,
                                               const float* __restrict__ w,
                                               int* cnt, float* sumw, int E) {
    int e = blockIdx.x * blockDim.x + threadIdx.x;
    if (e < E) {
        int d = dst[e];
        atomicAdd(&cnt[d], 1);
        atomicAdd(&sumw[d], w[e]);
    }
}

__global__ __launch_bounds__(256) void k_bsum(const int* __restrict__ cnt,
                                              int* __restrict__ bsum, int n) {
    const int i = blockIdx.x * 256 + threadIdx.x;
    const int lane = threadIdx.x & 63;
    int v = (i < n) ? cnt[i] : 0;
    v += __shfl_xor(v, 1, 64);
    v += __shfl_xor(v, 2, 64);
    v += __shfl_xor(v, 4, 64);
    v += __shfl_xor(v, 8, 64);
    v += __shfl_xor(v, 16, 64);
    v += __shfl_xor(v, 32, 64);
    __shared__ int ws[4];
    if (lane == 0) ws[threadIdx.x >> 6] = v;
    __syncthreads();
    if (threadIdx.x == 0)
        bsum[blockIdx.x] = ws[0] + ws[1] + ws[2] + ws[3];
}

__global__ __launch_bounds__(1024) void k_bscan(int* __restrict__ bsum,
                                                int* __restrict__ rowptrN, int nblk) {
    __shared__ int sd[1024];
    const int t = threadIdx.x;
    int v = (t < nblk) ? bsum[t] : 0;
    sd[t] = v;
    __syncthreads();
    for (int off = 1; off < 1024; off <<= 1) {
        int u = (t >= off) ? sd[t - off] : 0;
        __syncthreads();
        sd[t] += u;
        __syncthreads();
    }
    if (t < nblk) bsum[t] = sd[t] - v;
    if (t == 1023) *rowptrN = sd[1023];
}

__global__ __launch_bounds__(256) void k_rowptr(const int* __restrict__ cnt,
                                                const int* __restrict__ bsum,
                                                const float* __restrict__ sumw,
                                                int* __restrict__ rowptr,
                                                float* __restrict__ dinv,
                                                float* __restrict__ lattr, int n) {
    __shared__ int sd[256];
    const int t = threadIdx.x;
    const int i = blockIdx.x * 256 + t;
    int c = (i < n) ? cnt[i] : 0;
    sd[t] = c;
    __syncthreads();
    for (int off = 1; off < 256; off <<= 1) {
        int u = (t >= off) ? sd[t - off] : 0;
        __syncthreads();
        sd[t] += u;
        __syncthreads();
    }
    if (i < n) {
        rowptr[i] = bsum[blockIdx.x] + sd[t] - c;
        float sw = sumw[i];
        dinv[i] = rsqrtf(sw + 1.f);
        lattr[i] = (c > 0) ? sw / (float)c : 0.f;
    }
}

__global__ __launch_bounds__(256) void k_scatter(const int* __restrict__ src,
                                                 const int* __restrict__ dst,
                                                 const float* __restrict__ w,
                                                 const int* __restrict__ rowptr,
                                                 int* fill, int2* eSW, int E) {
    int e = blockIdx.x * blockDim.x + threadIdx.x;
    if (e < E) {
        int d = dst[e], s = src[e];
        int pos = rowptr[d] + atomicAdd(&fill[d], 1);
        eSW[pos] = make_int2(s, __float_as_int(w[e]));
    }
}

// weight conversion f32 -> bf16
__global__ __launch_bounds__(256) void k_cvtw(const float* __restrict__ W1,
                                              const float* __restrict__ Wl,
                                              const float* __restrict__ Wr,
                                              ushort* w1b, ushort* wlb, ushort* wrb) {
    int i = blockIdx.x * 256 + threadIdx.x;
    if (i < 4096) w1b[i] = f2bf(W1[i]);
    if (i < 8192) { wlb[i] = f2bf(Wl[i]); wrb[i] = f2bf(Wr[i]); }
}

// MFMA GEMM: hb[r,c] = x[r,:]·W1[c,:] (bf16 out). One wave per 16-row tile.
__global__ __launch_bounds__(256) void k_gemm_x(const float* __restrict__ X,
                                                const ushort* __restrict__ W1b,
                                                ushort* __restrict__ hb, int Mt) {
    const int wv = blockIdx.x * 4 + (threadIdx.x >> 6);
    if (wv >= Mt) return;
    const int lane = threadIdx.x & 63;
    const int r16 = lane & 15, kseg = lane >> 4;
    const float* xr = X + ((size_t)(wv * 16 + r16)) * 64 + kseg * 8;
    float4 x0 = *(const float4*)xr;
    float4 x1 = *(const float4*)(xr + 4);
    float4 x2 = *(const float4*)(xr + 32);
    float4 x3 = *(const float4*)(xr + 36);
    short8v a0, a1;
    a0[0] = (short)f2bf(x0.x); a0[1] = (short)f2bf(x0.y);
    a0[2] = (short)f2bf(x0.z); a0[3] = (short)f2bf(x0.w);
    a0[4] = (short)f2bf(x1.x); a0[5] = (short)f2bf(x1.y);
    a0[6] = (short)f2bf(x1.z); a0[7] = (short)f2bf(x1.w);
    a1[0] = (short)f2bf(x2.x); a1[1] = (short)f2bf(x2.y);
    a1[2] = (short)f2bf(x2.z); a1[3] = (short)f2bf(x2.w);
    a1[4] = (short)f2bf(x3.x); a1[5] = (short)f2bf(x3.y);
    a1[6] = (short)f2bf(x3.z); a1[7] = (short)f2bf(x3.w);
    const short8v* Wv = (const short8v*)W1b;
    f32x4 acc[4];
#pragma unroll
    for (int t = 0; t < 4; t++) acc[t] = (f32x4){0.f, 0.f, 0.f, 0.f};
#pragma unroll
    for (int t = 0; t < 4; t++) {
        int col = t * 16 + r16;
        acc[t] = __builtin_amdgcn_mfma_f32_16x16x32_bf16(a0, Wv[col * 8 + kseg], acc[t], 0, 0, 0);
        acc[t] = __builtin_amdgcn_mfma_f32_16x16x32_bf16(a1, Wv[col * 8 + 4 + kseg], acc[t], 0, 0, 0);
    }
#pragma unroll
    for (int t = 0; t < 4; t++)
#pragma unroll
        for (int i = 0; i < 4; i++)
            hb[((size_t)(wv * 16 + kseg * 4 + i)) * 64 + t * 16 + r16] = f2bf(acc[t][i]);
}

// MFMA dual GEMM: YL/YR[r,c] = A[r,:]·WL/WR[c,:] + BL/BR. A bf16 [M,64].
__global__ __launch_bounds__(256) void k_gemm_lr(const ushort* __restrict__ Ab,
                                                 const ushort* __restrict__ WLb,
                                                 const float* __restrict__ BL,
                                                 const ushort* __restrict__ WRb,
                                                 const float* __restrict__ BR,
                                                 ushort* __restrict__ YL,
                                                 ushort* __restrict__ YR, int Mt) {
    const int wv = blockIdx.x * 4 + (threadIdx.x >> 6);
    if (wv >= Mt) return;
    const int lane = threadIdx.x & 63;
    const int r16 = lane & 15, kseg = lane >> 4;
    const short8v* arow = (const short8v*)(Ab + ((size_t)(wv * 16 + r16)) * 64);
    short8v a0 = arow[kseg], a1 = arow[4 + kseg];
    const short8v* WvL = (const short8v*)WLb;
    const short8v* WvR = (const short8v*)WRb;
    f32x4 accL[8], accR[8];
#pragma unroll
    for (int t = 0; t < 8; t++) {
        accL[t] = (f32x4){0.f, 0.f, 0.f, 0.f};
        accR[t] = (f32x4){0.f, 0.f, 0.f, 0.f};
    }
#pragma unroll
    for (int t = 0; t < 8; t++) {
        int col = t * 16 + r16;
        accL[t] = __builtin_amdgcn_mfma_f32_16x16x32_bf16(a0, WvL[col * 8 + kseg], accL[t], 0, 0, 0);
        accL[t] = __builtin_amdgcn_mfma_f32_16x16x32_bf16(a1, WvL[col * 8 + 4 + kseg], accL[t], 0, 0, 0);
        accR[t] = __builtin_amdgcn_mfma_f32_16x16x32_bf16(a0, WvR[col * 8 + kseg], accR[t], 0, 0, 0);
        accR[t] = __builtin_amdgcn_mfma_f32_16x16x32_bf16(a1, WvR[col * 8 + 4 + kseg], accR[t], 0, 0, 0);
    }
#pragma unroll
    for (int t = 0; t < 8; t++) {
        int col = t * 16 + r16;
        float blv = BL[col], brv = BR[col];
#pragma unroll
        for (int i = 0; i < 4; i++) {
            size_t row = (size_t)(wv * 16 + kseg * 4 + i);
            YL[row * 128 + col] = f2bf(accL[t][i] + blv);
            YR[row * 128 + col] = f2bf(accR[t][i] + brv);
        }
    }
}

// GCN aggregate: grid-stride wave per node, 8-lane group per edge, record prefetch.
__global__ __launch_bounds__(256) void k_gcn_agg(const ushort* __restrict__ hb,
                                                 const int* __restrict__ rowptr,
                                                 const int2* __restrict__ eSW,
                                                 const float* __restrict__ dinv,
                                                 const float* __restrict__ b1,
                                                 ushort* __restrict__ hgb, int nN) {
    const int lane = threadIdx.x & 63;
    const int gwid = blockIdx.x * 4 + (threadIdx.x >> 6);
    const int nwv = gridDim.x * 4;
    const int g = lane >> 3, sub = lane & 7;
    const char* hB = (const char*)hb;
    const uint so = (uint)sub * 16u;

    for (int node = gwid; node < nN; node += nwv) {
        const float di = dinv[node];
        float acc[8] = {0.f, 0.f, 0.f, 0.f, 0.f, 0.f, 0.f, 0.f};
        const int beg = rowptr[node], endr = rowptr[node + 1];
        // prefetch first records
        int e0 = beg + g, e1 = e0 + 8;
        bool v0 = e0 < endr, v1 = e1 < endr;
        int2 q0 = v0 ? eSW[e0] : make_int2(node, 0);
        int2 q1 = v1 ? eSW[e1] : make_int2(node, 0);
        for (int base = beg; base < endr; base += 16) {
            // issue gathers for current records
            uint4 u0 = *(const uint4*)(hB + (((uint)q0.x) << 7) + so);
            uint4 u1 = *(const uint4*)(hB + (((uint)q1.x) << 7) + so);
            float n0 = v0 ? dinv[q0.x] * __int_as_float(q0.y) * di : 0.f;
            float n1 = v1 ? dinv[q1.x] * __int_as_float(q1.y) * di : 0.f;
            // prefetch next records (overlaps gather latency)
            int nb = base + 16;
            e0 = nb + g; e1 = e0 + 8;
            v0 = e0 < endr; v1 = e1 < endr;
            q0 = v0 ? eSW[e0] : make_int2(node, 0);
            q1 = v1 ? eSW[e1] : make_int2(node, 0);
            // compute
            float xa[8], xb[8];
            unp8(u0, xa); unp8(u1, xb);
#pragma unroll
            for (int j = 0; j < 8; j++)
                acc[j] = fmaf(n0, xa[j], fmaf(n1, xb[j], acc[j]));
        }
#pragma unroll
        for (int j = 0; j < 8; j++) {
            acc[j] += __shfl_xor(acc[j], 8, 64);
            acc[j] += __shfl_xor(acc[j], 16, 64);
            acc[j] += __shfl_xor(acc[j], 32, 64);
        }
        if (g == 0) {
            const int c0 = sub * 8;
            uint4 hv = *(const uint4*)(hB + (((uint)node) << 7) + so);
            float h8[8];
            unp8(hv, h8);
            float4 ba = *(const float4*)(b1 + c0);
            float4 bb = *(const float4*)(b1 + c0 + 4);
            float di2 = di * di;
            float o[8];
            o[0] = fmaxf(fmaf(di2, h8[0], acc[0]) + ba.x, 0.f);
            o[1] = fmaxf(fmaf(di2, h8[1], acc[1]) + ba.y, 0.f);
            o[2] = fmaxf(fmaf(di2, h8[2], acc[2]) + ba.z, 0.f);
            o[3] = fmaxf(fmaf(di2, h8[3], acc[3]) + ba.w, 0.f);
            o[4] = fmaxf(fmaf(di2, h8[4], acc[4]) + bb.x, 0.f);
            o[5] = fmaxf(fmaf(di2, h8[5], acc[5]) + bb.y, 0.f);
            o[6] = fmaxf(fmaf(di2, h8[6], acc[6]) + bb.z, 0.f);
            o[7] = fmaxf(fmaf(di2, h8[7], acc[7]) + bb.w, 0.f);
            uint4 ov;
            ov.x = pk2(o[0], o[1]);
            ov.y = pk2(o[2], o[3]);
            ov.z = pk2(o[4], o[5]);
            ov.w = pk2(o[6], o[7]);
            *(uint4*)((char*)hgb + (((uint)node) << 7) + so) = ov;
        }
    }
}

// Fused GATv2: grid-stride wave per node, 16-lane group per edge (8 ch/lane,
// head = sub>>2), 8 edges in flight + edge-record prefetch.
__global__ __launch_bounds__(256) void k_gat_fused(const uint* __restrict__ XL,
                                                   const uint* __restrict__ XR,
                                                   const int* __restrict__ rowptr,
                                                   const int2* __restrict__ eSW,
                                                   const float* __restrict__ lattr,
                                                   const float* __restrict__ We,
                                                   const float* __restrict__ att,
                                                   const float* __restrict__ bias_gat,
                                                   const float* __restrict__ x,
                                                   const float* __restrict__ Ws,
                                                   const float* __restrict__ bs,
                                                   const float* __restrict__ sgp,
                                                   float* __restrict__ out, int nN) {
    __shared__ float lds[4 * 608];
    const int lane = threadIdx.x & 63;
    const int wv = threadIdx.x >> 6;
    float* L = lds + wv * 608;
    const int g = lane >> 4, sub = lane & 15;
    const int hh = sub >> 2;
    const int c0 = sub * 8;
    const int gwid = blockIdx.x * 4 + wv;
    const int nwv = gridDim.x * 4;

    float We8[8], att8[8];
#pragma unroll
    for (int j = 0; j < 8; j++) { We8[j] = We[c0 + j]; att8[j] = att[c0 + j]; }
    const int cs = lane & 31, h0 = lane >> 5;
    const float bgv = bias_gat[cs], bsv = bs[cs], sgv = sgp[0];
    const char* XLb = (const char*)XL;
    const ushort* XLus = (const ushort*)XL;
    const uint so = (uint)sub * 16u;

    for (int node = gwid; node < nN; node += nwv) {
        uint4 ur = *(const uint4*)((const char*)XR + (((uint)node) << 8) + so);
        float xr8[8];
        unp8(ur, xr8);

        float acc[8] = {0.f, 0.f, 0.f, 0.f, 0.f, 0.f, 0.f, 0.f};
        float den = 0.f;
        const int beg = rowptr[node], endr = rowptr[node + 1];
        // prefetch first records
        int e0 = beg + g, e1 = e0 + 4;
        bool v0 = e0 < endr, v1 = e1 < endr;
        int2 q0 = v0 ? eSW[e0] : make_int2(node, 0);
        int2 q1 = v1 ? eSW[e1] : make_int2(node, 0);
        for (int base = beg; base < endr; base += 8) {
            // issue gathers for current records
            uint4 u0 = *(const uint4*)(XLb + (((uint)q0.x) << 8) + so);
            uint4 u1 = *(const uint4*)(XLb + (((uint)q1.x) << 8) + so);
            float w0 = __int_as_float(q0.y), w1 = __int_as_float(q1.y);
            bool cv0 = v0, cv1 = v1;
            // prefetch next records (overlaps gather latency)
            int nb = base + 8;
            e0 = nb + g; e1 = e0 + 4;
            v0 = e0 < endr; v1 = e1 < endr;
            q0 = v0 ? eSW[e0] : make_int2(node, 0);
            q1 = v1 ? eSW[e1] : make_int2(node, 0);
            // compute
            float xa[8], xb[8];
            unp8(u0, xa); unp8(u1, xb);
            float t0 = 0.f, t1 = 0.f;
#pragma unroll
            for (int j = 0; j < 8; j++) {
                float s = xr8[j], aj = att8[j], wj = We8[j];
                t0 = fmaf(lrelu(fmaf(w0, wj, xa[j] + s)), aj, t0);
                t1 = fmaf(lrelu(fmaf(w1, wj, xb[j] + s)), aj, t1);
            }
            t0 = red4(t0);
            t1 = red4(t1);
            float ex0 = cv0 ? __expf(t0) : 0.f;
            float ex1 = cv1 ? __expf(t1) : 0.f;
            den += ex0 + ex1;
#pragma unroll
            for (int j = 0; j < 8; j++)
                acc[j] = fmaf(ex0, xa[j], fmaf(ex1, xb[j], acc[j]));
        }

        // self-loop alpha (identical across groups)
        float la = lattr[node];
        uint4 un = *(const uint4*)(XLb + (((uint)node) << 8) + so);
        float xn[8];
        unp8(un, xn);
        float ts = 0.f;
#pragma unroll
        for (int j = 0; j < 8; j++)
            ts = fmaf(lrelu(fmaf(la, We8[j], xn[j] + xr8[j])), att8[j], ts);
        ts = red4(ts);
        float es = __expf(ts);

        // stash partials in wave-private LDS (stride 9)
#pragma unroll
        for (int j = 0; j < 8; j++) L[lane * 9 + j] = acc[j];
        if ((sub & 3) == 0) L[576 + g * 4 + hh] = den;
        if (g == 0 && (sub & 3) == 0) L[592 + hh] = es;

        // epilogue: head-mean + self-loop + skip
        float th = 0.f;
#pragma unroll
        for (int hd = 0; hd < 4; hd++) {
            int bl = hd * 4 + (cs >> 3);
            int j = cs & 7;
            float a = L[bl * 9 + j] + L[(16 + bl) * 9 + j] +
                      L[(32 + bl) * 9 + j] + L[(48 + bl) * 9 + j];
            float dn = L[576 + hd] + L[580 + hd] + L[584 + hd] + L[588 + hd];
            float eh = L[592 + hd];
            float xc = bfu(XLus[(size_t)node * 128 + hd * 32 + cs]);
            th += (a + eh * xc) / (dn + eh + 1e-16f);
        }
        const float4* xp = (const float4*)(x + (size_t)node * 64 + h0 * 32);
        const float4* wp = (const float4*)(Ws + (size_t)cs * 64 + h0 * 32);
        float sk = 0.f;
#pragma unroll
        for (int q = 0; q < 8; q++) {
            float4 xq = xp[q], wq = wp[q];
            sk += xq.x * wq.x + xq.y * wq.y + xq.z * wq.z + xq.w * wq.w;
        }
        sk += __shfl_xor(sk, 32, 64);
        float res = th * 0.25f + bgv + sgv * (sk + bsv);
        if (lane < 32) out[(size_t)node * 32 + cs] = res;
    }
}

// ---------- launch ----------
extern "C" void kernel_launch(void* const* d_in, const int* in_sizes, int n_in,
                              void* d_out, int out_size, void* d_ws, size_t ws_size,
                              hipStream_t stream) {
    const float* x        = (const float*)d_in[0];
    const int*   ei       = (const int*)d_in[1];
    const float* ew       = (const float*)d_in[2];
    const float* W1       = (const float*)d_in[3];
    const float* b1       = (const float*)d_in[4];
    const float* Wl       = (const float*)d_in[5];
    const float* bl       = (const float*)d_in[6];
    const float* Wr       = (const float*)d_in[7];
    const float* br       = (const float*)d_in[8];
    const float* We       = (const float*)d_in[9];
    const float* att      = (const float*)d_in[10];
    const float* bias_gat = (const float*)d_in[11];
    const float* Ws       = (const float*)d_in[12];
    const float* bs       = (const float*)d_in[13];
    const float* sg       = (const float*)d_in[14];

    const int N = in_sizes[0] / 64;
    const int E = in_sizes[2];
    const int* srcI = ei;
    const int* dstI = ei + E;
    const int nblk = (N + 255) / 256;
    const int Mt = (N + 15) / 16;

    char* p = (char*)d_ws;
    auto alloc = [&](size_t bytes) {
        void* r = (void*)p;
        p += (bytes + 255) & ~(size_t)255;
        return r;
    };
    int*    cnt    = (int*)alloc((size_t)N * 4);
    int*    fill   = (int*)alloc((size_t)N * 4);
    int*    rowptr = (int*)alloc((size_t)(N + 1) * 4);
    int*    bsum   = (int*)alloc((size_t)nblk * 4);
    int2*   eSW    = (int2*)alloc((size_t)E * 8);
    float*  sumw   = (float*)alloc((size_t)N * 4);
    float*  dinv   = (float*)alloc((size_t)N * 4);
    float*  lattr  = (float*)alloc((size_t)N * 4);
    ushort* hb     = (ushort*)alloc((size_t)Mt * 16 * 64 * 2);
    ushort* hgb    = (ushort*)alloc((size_t)Mt * 16 * 64 * 2);
    ushort* xl_bf  = (ushort*)alloc((size_t)Mt * 16 * 128 * 2);
    ushort* xr_bf  = (ushort*)alloc((size_t)Mt * 16 * 128 * 2);
    ushort* w1b    = (ushort*)alloc(4096 * 2);
    ushort* wlb    = (ushort*)alloc(8192 * 2);
    ushort* wrb    = (ushort*)alloc(8192 * 2);
    if ((size_t)(p - (char*)d_ws) > ws_size) return;

    hipMemsetAsync(cnt, 0, (size_t)N * 4, stream);
    hipMemsetAsync(fill, 0, (size_t)N * 4, stream);
    hipMemsetAsync(sumw, 0, (size_t)N * 4, stream);
    k_count<<<(E + 255) / 256, 256, 0, stream>>>(dstI, ew, cnt, sumw, E);
    k_bsum<<<nblk, 256, 0, stream>>>(cnt, bsum, N);
    k_bscan<<<1, 1024, 0, stream>>>(bsum, rowptr + N, nblk);
    k_rowptr<<<nblk, 256, 0, stream>>>(cnt, bsum, sumw, rowptr, dinv, lattr, N);
    k_scatter<<<(E + 255) / 256, 256, 0, stream>>>(srcI, dstI, ew, rowptr,
                                                   fill, eSW, E);
    k_cvtw<<<32, 256, 0, stream>>>(W1, Wl, Wr, w1b, wlb, wrb);
    k_gemm_x<<<(Mt + 3) / 4, 256, 0, stream>>>(x, w1b, hb, Mt);
    k_gcn_agg<<<2048, 256, 0, stream>>>(hb, rowptr, eSW, dinv, b1, hgb, N);
    k_gemm_lr<<<(Mt + 3) / 4, 256, 0, stream>>>(hgb, wlb, bl, wrb, br,
                                                xl_bf, xr_bf, Mt);
    k_gat_fused<<<2048, 256, 0, stream>>>((const uint*)xl_bf, (const uint*)xr_bf,
                                          rowptr, eSW, lattr, We, att,
                                          bias_gat, x, Ws, bs, sg,
                                          (float*)d_out, N);
}